// Round 12
// baseline (578.025 us; speedup 1.0000x reference)
//
#include <hip/hip_runtime.h>
#include <math.h>

#define NN 100000
#define EE 800000
#define ET (EE + NN)
#define BS 256
#define BKTS 391        // cdiv(NN, 256) coarse buckets (dst >> 8)
#define FB_EPB 4096     // edges per block in hist/fill passes
#define LDSCAP 4096     // max edges per bucket (mean 2303, sigma ~45)

typedef _Float16 f16;
typedef __attribute__((ext_vector_type(4))) _Float16 half4;
typedef __attribute__((ext_vector_type(8))) _Float16 half8;
typedef __attribute__((ext_vector_type(4))) float f32x4;
template<int V> struct HV;
template<> struct HV<4>{ typedef half4 type; };
template<> struct HV<8>{ typedef half8 type; };

static inline int cdiv(long a, int b){ return (int)((a + b - 1) / b); }

// ---------------- CSR build: 2-level counting sort (no per-dst atomics) ----------------
__global__ __launch_bounds__(256) void k_bhist(const int* __restrict__ ei,
                                               int* __restrict__ bucketCount){
    __shared__ int hist[BKTS];
    for (int t = threadIdx.x; t < BKTS; t += 256) hist[t] = 0;
    __syncthreads();
    const int e0 = blockIdx.x * FB_EPB + threadIdx.x;
    #pragma unroll
    for (int i = 0; i < 16; i++){
        int e = e0 + i * 256;
        if (e < ET){
            int d = (e < EE) ? ei[EE + e] : (e - EE);
            atomicAdd(&hist[d >> 8], 1);
        }
    }
    __syncthreads();
    for (int t = threadIdx.x; t < BKTS; t += 256){
        int c = hist[t];
        if (c) atomicAdd(&bucketCount[t], c);
    }
}

__global__ void k_bscan(const int* __restrict__ bucketCount, int* __restrict__ bucketBase,
                        int* __restrict__ bucketCursor, int* __restrict__ rowptr){
    __shared__ int sh[512];
    int t = threadIdx.x;
    int c = (t < BKTS) ? bucketCount[t] : 0;
    sh[t] = c;
    __syncthreads();
    for (int o = 1; o < 512; o <<= 1){
        int v = (t >= o) ? sh[t - o] : 0;
        __syncthreads();
        sh[t] += v;
        __syncthreads();
    }
    if (t < BKTS){
        int excl = sh[t] - c;
        bucketBase[t] = excl;
        bucketCursor[t] = excl;
    }
    if (t == 0){
        bucketBase[BKTS] = ET;
        rowptr[NN] = ET;
    }
}

__global__ __launch_bounds__(256) void k_bfill(const int* __restrict__ ei,
        int* __restrict__ bucketCursor, unsigned* __restrict__ bpack){
    __shared__ int hist[BKTS];
    __shared__ int base[BKTS];
    for (int t = threadIdx.x; t < BKTS; t += 256) hist[t] = 0;
    __syncthreads();
    const int e0 = blockIdx.x * FB_EPB + threadIdx.x;
    unsigned pk[16], rb[16];
    #pragma unroll
    for (int i = 0; i < 16; i++){
        int e = e0 + i * 256;
        rb[i] = 0xFFFFFFFFu;
        if (e < ET){
            int s, d;
            if (e < EE){ s = ei[e]; d = ei[EE + e]; } else { s = e - EE; d = s; }
            int b = d >> 8;
            int r = atomicAdd(&hist[b], 1);
            pk[i] = ((unsigned)(d & 255) << 17) | (unsigned)s;
            rb[i] = ((unsigned)r << 9) | (unsigned)b;
        }
    }
    __syncthreads();
    for (int t = threadIdx.x; t < BKTS; t += 256){
        int c = hist[t];
        base[t] = c ? atomicAdd(&bucketCursor[t], c) : 0;
    }
    __syncthreads();
    #pragma unroll
    for (int i = 0; i < 16; i++){
        if (rb[i] != 0xFFFFFFFFu){
            int b = rb[i] & 511;
            int r = rb[i] >> 9;
            bpack[base[b] + r] = pk[i];
        }
    }
}

// Pass 4: block per bucket: LDS counting-sort by dstlow; coalesced rowptr+ssrc+sdst.
__global__ __launch_bounds__(256) void k_bsort(const unsigned* __restrict__ bpack,
        const int* __restrict__ bucketBase, int* __restrict__ rowptr,
        int* __restrict__ ssrc, int* __restrict__ sdst){
    __shared__ int cnt[256];
    __shared__ int off[256];
    __shared__ unsigned stage[LDSCAP];
    int b = blockIdx.x;
    int n0 = bucketBase[b], n1 = bucketBase[b + 1];
    int nE = n1 - n0;
    int t = threadIdx.x;
    cnt[t] = 0;
    __syncthreads();
    for (int i = t; i < nE; i += 256){
        unsigned v = bpack[n0 + i];
        atomicAdd(&cnt[v >> 17], 1);
    }
    __syncthreads();
    int cv = cnt[t];
    off[t] = cv;
    __syncthreads();
    for (int o = 1; o < 256; o <<= 1){
        int v = (t >= o) ? off[t - o] : 0;
        __syncthreads();
        off[t] += v;
        __syncthreads();
    }
    int excl = off[t] - cv;
    __syncthreads();
    off[t] = excl;
    cnt[t] = 0;
    __syncthreads();
    for (int i = t; i < nE; i += 256){
        unsigned v = bpack[n0 + i];
        int dl = v >> 17;
        int r = atomicAdd(&cnt[dl], 1);
        stage[off[dl] + r] = v;
    }
    int d = b * 256 + t;
    if (d < NN) rowptr[d] = n0 + excl;
    __syncthreads();
    for (int i = t; i < nE; i += 256){
        unsigned v = stage[i];
        ssrc[n0 + i] = (int)(v & 0x1FFFFu);
        sdst[n0 + i] = b * 256 + (int)(v >> 17);
    }
}

// ---------------- prep (all layers in one kernel) ----------------
template<int K, int M, int KP, int MP, int HH, int CC>
__device__ __forceinline__ void prep_one(int idx, const float* __restrict__ W,
        const float* __restrict__ b, const float* __restrict__ as_,
        const float* __restrict__ ad_, f16* __restrict__ Wpk,
        float* __restrict__ bp, float* __restrict__ Was, float* __restrict__ Wad){
    constexpr int NT = MP / 16;
    if (idx < KP * MP){
        int j    = idx & 7;
        int lane = (idx >> 3) & 63;
        int rest = idx >> 9;
        int nt   = rest % NT;
        int ks   = rest / NT;
        int k = ks * 32 + ((lane >> 4) & 3) * 8 + j;
        int n = nt * 16 + (lane & 15);
        Wpk[idx] = (k < K && n < M) ? (f16)W[k * M + n] : (f16)0.f;
    }
    if (idx < MP) bp[idx] = (idx < M) ? b[idx] : 0.f;
    if (idx < K * HH){
        int k = idx / HH, hd = idx - k * HH;
        float s = 0.f, d = 0.f;
        #pragma unroll
        for (int c = 0; c < CC; c++){
            float w = W[k * M + hd * CC + c];
            s = fmaf(w, as_[hd * CC + c], s);
            d = fmaf(w, ad_[hd * CC + c], d);
        }
        Was[idx] = s;
        Wad[idx] = d;
    }
}

__device__ __forceinline__ void prep_w0(int idx, const float* __restrict__ W0,
                                        f16* __restrict__ Wpk0){
    int j    = idx & 7;
    int lane = (idx >> 3) & 63;
    int nt   = (idx >> 9) & 1;
    int hd   = idx >> 10;
    int k    = ((lane >> 4) & 3) * 8 + j;
    int cih  = nt * 16 + (lane & 15);
    Wpk0[idx] = (cih < 24) ? (f16)W0[k * 240 + hd * 24 + cih] : (f16)0.f;
}

struct PrepAll {
    const float *W[5], *b[5], *as[5], *ad[5];
    f16*   Wpk[5];
    f16*   Wpk0;
    float* bp[5];
    float* Was[5];
    float* Wad[5];
    int*   bucketCount;
};

__global__ void k_prep_all(PrepAll a){
    int idx = blockIdx.x * 256 + threadIdx.x;
    if (idx < 7680)
        prep_one< 32, 240,  32, 240, 10, 24>(idx,         a.W[0], a.b[0], a.as[0], a.ad[0], a.Wpk[0], a.bp[0], a.Was[0], a.Wad[0]);
    else if (idx < 40448)
        prep_one<240, 120, 256, 128,  5, 24>(idx - 7680,  a.W[1], a.b[1], a.as[1], a.ad[1], a.Wpk[1], a.bp[1], a.Was[1], a.Wad[1]);
    else if (idx < 48640)
        prep_one<120,  48, 128,  64,  2, 24>(idx - 40448, a.W[2], a.b[2], a.as[2], a.ad[2], a.Wpk[2], a.bp[2], a.Was[2], a.Wad[2]);
    else if (idx < 50688)
        prep_one< 48,  24,  64,  32,  1, 24>(idx - 48640, a.W[3], a.b[3], a.as[3], a.ad[3], a.Wpk[3], a.bp[3], a.Was[3], a.Wad[3]);
    else if (idx < 51200)
        prep_one< 24,  12,  32,  16,  1, 12>(idx - 50688, a.W[4], a.b[4], a.as[4], a.ad[4], a.Wpk[4], a.bp[4], a.Was[4], a.Wad[4]);
    else if (idx < 61440)
        prep_w0(idx - 51200, a.W[0], a.Wpk0);
    else if (idx < 61440 + BKTS)
        a.bucketCount[idx - 61440] = 0;
}

// ---------------- L0: fused X0 fp32->fp16 convert + alpha logits ----------------
__global__ void k_cvt_alpha0(const float* __restrict__ X, f16* __restrict__ Xh,
                             const float* __restrict__ Was, const float* __restrict__ Wad,
                             float* __restrict__ als, float* __restrict__ ald){
    int n = blockIdx.x * BS + threadIdx.x;
    if (n >= NN) return;
    float xr[32];
    #pragma unroll
    for (int i = 0; i < 8; i++){
        float4 v = *(const float4*)(X + (long)n * 32 + i * 4);
        xr[i * 4 + 0] = v.x; xr[i * 4 + 1] = v.y;
        xr[i * 4 + 2] = v.z; xr[i * 4 + 3] = v.w;
    }
    #pragma unroll
    for (int i = 0; i < 4; i++){
        half8 h;
        #pragma unroll
        for (int c = 0; c < 8; c++) h[c] = (f16)xr[i * 8 + c];
        *(half8*)(Xh + (long)n * 32 + i * 8) = h;
    }
    float s[10] = {}, d[10] = {};
    for (int k = 0; k < 32; k++){
        float x = xr[k];
        #pragma unroll
        for (int hd = 0; hd < 10; hd++){
            s[hd] = fmaf(x, Was[k * 10 + hd], s[hd]);
            d[hd] = fmaf(x, Wad[k * 10 + hd], d[hd]);
        }
    }
    #pragma unroll
    for (int hd = 0; hd < 10; hd++){
        als[n * 10 + hd] = s[hd];
        ald[n * 10 + hd] = d[hd];
    }
}

// ---------------- softmax state m, 1/z per (dst, head): 2 passes ----------------
template<int HH>
__global__ void k_mz2(const float* __restrict__ als, const float* __restrict__ ald,
                      const int* __restrict__ rowptr, const int* __restrict__ ssrc,
                      float* __restrict__ marr, float* __restrict__ zinvarr){
    int idx = blockIdx.x * BS + threadIdx.x;
    if (idx >= NN * HH) return;
    int n = idx / HH, hd = idx - n * HH;
    float adv = ald[idx];
    int beg = rowptr[n], end = rowptr[n + 1];
    float ma = -1e30f;
    for (int p = beg; p < end; p++)
        ma = fmaxf(ma, als[ssrc[p] * HH + hd]);
    float m = ma + adv;
    m = (m >= 0.f) ? m : 0.2f * m;
    float z = 0.f;
    for (int p = beg; p < end; p++){
        float e = als[ssrc[p] * HH + hd] + adv;
        e = (e >= 0.f) ? e : 0.2f * e;
        z += __expf(e - m);
    }
    marr[idx] = m;
    zinvarr[idx] = 1.f / z;
}

// ---------------- edge-parallel normalized attention (L0/L1): coalesced writes ----------------
template<int HH, int ATTS, bool GROUPED>
__global__ __launch_bounds__(256) void k_att_edge(const float* __restrict__ als,
        const float* __restrict__ ald, const float* __restrict__ marr,
        const float* __restrict__ zinv, const int* __restrict__ ssrc,
        const int* __restrict__ sdst, f16* __restrict__ att){
    int p = blockIdx.x * 256 + threadIdx.x;
    if (p >= ET) return;
    int s = ssrc[p], d = sdst[p];
    float w[HH];
    #pragma unroll
    for (int hd = 0; hd < HH; hd++){
        float e = als[s * HH + hd] + ald[d * HH + hd];
        e = (e >= 0.f) ? e : 0.2f * e;
        w[hd] = __expf(e - marr[d * HH + hd]) * zinv[d * HH + hd];
    }
    if constexpr (GROUPED){                 // HH==10, ATTS==16: heads 0-4 | 5-9
        half8 lo = {}, hi = {};
        #pragma unroll
        for (int h = 0; h < 5; h++){ lo[h] = (f16)w[h]; hi[h] = (f16)w[h + 5]; }
        *(half8*)(att + (long)p * 16)     = lo;
        *(half8*)(att + (long)p * 16 + 8) = hi;
    } else {                                // HH==5, ATTS==8
        half8 v = {};
        #pragma unroll
        for (int h = 0; h < HH; h++) v[h] = (f16)w[h];
        *(half8*)(att + (long)p * ATTS) = v;
    }
}

// ---------------- fused 3-pass mz+att (kept for HH<=2) ----------------
template<int HH, int ATTS>
__global__ void k_mz_att(const float* __restrict__ als, const float* __restrict__ ald,
                         const int* __restrict__ rowptr, const int* __restrict__ ssrc,
                         f16* __restrict__ att){
    int idx = blockIdx.x * BS + threadIdx.x;
    if (idx >= NN * HH) return;
    int n = idx / HH, hd = idx - n * HH;
    float adv = ald[idx];
    int beg = rowptr[n], end = rowptr[n + 1];
    float ma = -1e30f;
    for (int p = beg; p < end; p++)
        ma = fmaxf(ma, als[ssrc[p] * HH + hd]);
    float m = ma + adv;
    m = (m >= 0.f) ? m : 0.2f * m;
    float z = 0.f;
    for (int p = beg; p < end; p++){
        float e = als[ssrc[p] * HH + hd] + adv;
        e = (e >= 0.f) ? e : 0.2f * e;
        z += __expf(e - m);
    }
    float zinv = 1.f / z;
    for (int p = beg; p < end; p++){
        float e = als[ssrc[p] * HH + hd] + adv;
        e = (e >= 0.f) ? e : 0.2f * e;
        att[(long)p * ATTS + hd] = (f16)(__expf(e - m) * zinv);
    }
}

// ---------------- L0: aggregate X: Xagg[n,hd,k] = sum_s att * X[s,k] ----------------
__global__ __launch_bounds__(256) void k_aggX0(const f16* __restrict__ Xh,
        const f16* __restrict__ att, const int* __restrict__ rowptr,
        const int* __restrict__ ssrc, f16* __restrict__ Xagg){
    int idx = blockIdx.x * 256 + threadIdx.x;
    if (idx >= NN * 8) return;
    int n = idx >> 3;
    int hg = (idx >> 2) & 1;
    int ch = idx & 3;
    float acc[5][8] = {};
    int beg = rowptr[n], end = rowptr[n + 1];
    int p = beg;
    for (; p + 2 <= end; p += 2){
        int s0 = ssrc[p], s1 = ssrc[p + 1];
        half8 x0 = *(const half8*)(Xh + (long)s0 * 32 + ch * 8);
        half8 x1 = *(const half8*)(Xh + (long)s1 * 32 + ch * 8);
        half8 a0 = *(const half8*)(att + (long)p * 16 + hg * 8);
        half8 a1 = *(const half8*)(att + (long)(p + 1) * 16 + hg * 8);
        #pragma unroll
        for (int h = 0; h < 5; h++){
            float w0 = (float)a0[h], w1 = (float)a1[h];
            #pragma unroll
            for (int c = 0; c < 8; c++){
                acc[h][c] = fmaf(w0, (float)x0[c], acc[h][c]);
                acc[h][c] = fmaf(w1, (float)x1[c], acc[h][c]);
            }
        }
    }
    if (p < end){
        int s = ssrc[p];
        half8 xv = *(const half8*)(Xh + (long)s * 32 + ch * 8);
        half8 av = *(const half8*)(att + (long)p * 16 + hg * 8);
        #pragma unroll
        for (int h = 0; h < 5; h++){
            float w = (float)av[h];
            #pragma unroll
            for (int c = 0; c < 8; c++)
                acc[h][c] = fmaf(w, (float)xv[c], acc[h][c]);
        }
    }
    #pragma unroll
    for (int h = 0; h < 5; h++){
        half8 o;
        #pragma unroll
        for (int c = 0; c < 8; c++) o[c] = (f16)acc[h][c];
        *(half8*)(Xagg + (long)n * 320 + (hg * 5 + h) * 32 + ch * 8) = o;
    }
}

// ---------------- L0: block-diagonal MFMA GEMM: X1 = relu(Xagg @bd W0 + b) ----------------
__global__ __launch_bounds__(256) void k_gemmX0(const f16* __restrict__ Xagg,
        const f16* __restrict__ Wpk0, const float* __restrict__ bp0,
        f16* __restrict__ X1){
    const int wave = threadIdx.x >> 6;
    const int lane = threadIdx.x & 63;
    const int quad = lane >> 4;
    const int l16  = lane & 15;
    const int hd   = blockIdx.y;
    const long row0 = (long)blockIdx.x * 128 + wave * 32;
    const long r0 = row0 + l16;
    const long r1 = r0 + 16;
    const half8 hz = {};
    half8 a0 = (r0 < NN) ? *(const half8*)(Xagg + r0 * 320 + hd * 32 + quad * 8) : hz;
    half8 a1 = (r1 < NN) ? *(const half8*)(Xagg + r1 * 320 + hd * 32 + quad * 8) : hz;
    f32x4 acc[2][2];
    #pragma unroll
    for (int mt = 0; mt < 2; mt++)
        #pragma unroll
        for (int nt = 0; nt < 2; nt++)
            acc[mt][nt] = (f32x4){0.f, 0.f, 0.f, 0.f};
    #pragma unroll
    for (int nt = 0; nt < 2; nt++){
        half8 bfr = *(const half8*)(Wpk0 + ((hd * 2 + nt) * 64 + lane) * 8);
        acc[0][nt] = __builtin_amdgcn_mfma_f32_16x16x32_f16(a0, bfr, acc[0][nt], 0, 0, 0);
        acc[1][nt] = __builtin_amdgcn_mfma_f32_16x16x32_f16(a1, bfr, acc[1][nt], 0, 0, 0);
    }
    #pragma unroll
    for (int mt = 0; mt < 2; mt++){
        #pragma unroll
        for (int reg = 0; reg < 4; reg++){
            long r = row0 + mt * 16 + quad * 4 + reg;
            if (r < NN){
                #pragma unroll
                for (int nt = 0; nt < 2; nt++){
                    int cih = nt * 16 + l16;
                    if (cih < 24){
                        int j = hd * 24 + cih;
                        float v = acc[mt][nt][reg] + bp0[j];
                        X1[r * 256 + j] = (f16)((v > 0.f) ? v : 0.f);
                    }
                }
            }
        }
    }
}

// ---------------- MFMA GEMM v3 (layers 1..4): 64 rows/block (1 m-tile/wave),
// A-prefetch, B from L2-resident Wpk, split-K alpha tail ----------------
template<int K, int KP, int MPH, int HH>
__global__ __launch_bounds__(256) void k_gemm_mfma(const f16* __restrict__ Xh,
        const f16* __restrict__ Wpk, f16* __restrict__ H2,
        const float* __restrict__ Was, const float* __restrict__ Wad,
        float* __restrict__ als, float* __restrict__ ald){
    constexpr int NT = MPH / 16;
    constexpr int KS = KP / 32;
    const int wave = threadIdx.x >> 6;
    const int lane = threadIdx.x & 63;
    const int quad = lane >> 4;
    const int l16  = lane & 15;
    const long row0 = (long)blockIdx.x * 64 + wave * 16;

    f32x4 acc[NT];
    #pragma unroll
    for (int nt = 0; nt < NT; nt++)
        acc[nt] = (f32x4){0.f, 0.f, 0.f, 0.f};

    const long r0 = row0 + l16;
    const half8 hz = {};
    half8 a0 = (r0 < NN) ? *(const half8*)(Xh + r0 * KP + quad * 8) : hz;   // prefetch ks=0
    for (int ks = 0; ks < KS; ks++){
        half8 nx = hz;
        if (ks + 1 < KS){
            const int kk = (ks + 1) * 32 + quad * 8;
            nx = (r0 < NN) ? *(const half8*)(Xh + r0 * KP + kk) : hz;
        }
        const f16* bp_ = Wpk + ((long)ks * NT * 64 + lane) * 8;
        #pragma unroll
        for (int nt = 0; nt < NT; nt++){
            half8 bfr = *(const half8*)(bp_ + (long)nt * 512);
            acc[nt] = __builtin_amdgcn_mfma_f32_16x16x32_f16(a0, bfr, acc[nt], 0, 0, 0);
        }
        a0 = nx;
    }
    #pragma unroll
    for (int reg = 0; reg < 4; reg++){
        long r = row0 + quad * 4 + reg;
        if (r < NN){
            #pragma unroll
            for (int nt = 0; nt < NT; nt++)
                H2[r * MPH + nt * 16 + l16] = (f16)acc[nt][reg];
        }
    }

    // ---- alpha logits: threads 0..127, 2 per row (split-K), shfl-combined ----
    if (threadIdx.x < 128){
        constexpr int KH = K / 2;               // 120/60/24/12 — all %4 == 0
        int t = threadIdx.x;
        long n = (long)blockIdx.x * 64 + (t >> 1);
        int kbase = (t & 1) * KH;
        float s[HH] = {}, d[HH] = {};
        if (n < NN){
            const f16* x = Xh + n * KP + kbase;
            for (int k = 0; k < KH; k += 4){
                half4 xv = *(const half4*)(x + k);
                float xf0 = (float)xv[0], xf1 = (float)xv[1];
                float xf2 = (float)xv[2], xf3 = (float)xv[3];
                const float* wsp = Was + (long)(kbase + k) * HH;
                const float* wdp = Wad + (long)(kbase + k) * HH;
                #pragma unroll
                for (int hd = 0; hd < HH; hd++){
                    s[hd] = fmaf(xf0, wsp[0 * HH + hd], s[hd]);
                    s[hd] = fmaf(xf1, wsp[1 * HH + hd], s[hd]);
                    s[hd] = fmaf(xf2, wsp[2 * HH + hd], s[hd]);
                    s[hd] = fmaf(xf3, wsp[3 * HH + hd], s[hd]);
                    d[hd] = fmaf(xf0, wdp[0 * HH + hd], d[hd]);
                    d[hd] = fmaf(xf1, wdp[1 * HH + hd], d[hd]);
                    d[hd] = fmaf(xf2, wdp[2 * HH + hd], d[hd]);
                    d[hd] = fmaf(xf3, wdp[3 * HH + hd], d[hd]);
                }
            }
        }
        #pragma unroll
        for (int hd = 0; hd < HH; hd++){
            s[hd] += __shfl_xor(s[hd], 1);
            d[hd] += __shfl_xor(d[hd], 1);
        }
        if ((t & 1) == 0 && n < NN){
            #pragma unroll
            for (int hd = 0; hd < HH; hd++){
                als[n * HH + hd] = s[hd];
                ald[n * HH + hd] = d[hd];
            }
        }
    }
}

// ---------------- fused aggregate via precomputed att (layers 1..4) ----------------
template<int HH, int CC, int ATTS, int MPH, int MPO, int VEC, bool O16>
__global__ __launch_bounds__(256) void k_agg_h(const f16* __restrict__ H2,
        const f16* __restrict__ att,
        const int* __restrict__ rowptr, const int* __restrict__ ssrc,
        const float* __restrict__ bp, f16* __restrict__ out16,
        float* __restrict__ out32, int MREAL){
    constexpr int TPN = MPO / VEC;
    typedef typename HV<VEC>::type hvec;
    int idx = blockIdx.x * 256 + threadIdx.x;
    if (idx >= NN * TPN) return;
    int n = idx / TPN;
    int q = idx - n * TPN;
    int j0 = q * VEC;
    if constexpr (O16 && (MPO > MPH)){
        if (j0 >= MPH){
            hvec zv = {};
            *(hvec*)(out16 + (long)n * MPO + j0) = zv;
            return;
        }
    }
    int hd = j0 / CC; if (hd > HH - 1) hd = HH - 1;

    int beg = rowptr[n], end = rowptr[n + 1];
    float acc[VEC] = {};
    int p = beg;
    for (; p + 2 <= end; p += 2){
        int s0 = ssrc[p], s1 = ssrc[p + 1];
        float w0 = (float)att[(long)p * ATTS + hd];
        float w1 = (float)att[(long)(p + 1) * ATTS + hd];
        hvec h0 = *(const hvec*)(H2 + (long)s0 * MPH + j0);
        hvec h1 = *(const hvec*)(H2 + (long)s1 * MPH + j0);
        #pragma unroll
        for (int c = 0; c < VEC; c++){
            acc[c] = fmaf(w0, (float)h0[c], acc[c]);
            acc[c] = fmaf(w1, (float)h1[c], acc[c]);
        }
    }
    if (p < end){
        int s = ssrc[p];
        float w = (float)att[(long)p * ATTS + hd];
        hvec hv = *(const hvec*)(H2 + (long)s * MPH + j0);
        #pragma unroll
        for (int c = 0; c < VEC; c++)
            acc[c] = fmaf(w, (float)hv[c], acc[c]);
    }
    if constexpr (O16){
        hvec o;
        #pragma unroll
        for (int c = 0; c < VEC; c++){
            float v = acc[c] + bp[j0 + c];
            o[c] = (f16)((v > 0.f) ? v : 0.f);
        }
        *(hvec*)(out16 + (long)n * MPO + j0) = o;
    } else {
        if (j0 < MREAL){
            #pragma unroll
            for (int c = 0; c < VEC; c++){
                float v = acc[c] + bp[j0 + c];
                out32[(long)n * MREAL + j0 + c] = (v > 0.f) ? v : 0.f;
            }
        }
    }
}

// ---------------- layer driver (layers 1..4) ----------------
template<int K, int M, int KP, int MPH, int MPO, int HH, int CC, int ATTS, int VEC,
         bool O16, bool EDGEATT>
static void run_layer(const f16* Xh, f16* H2, f16* att,
                      const f16* Wpk, const float* bp, const float* Was, const float* Wad,
                      float* als, float* ald, float* marr, float* zinv,
                      const int* rowptr, const int* ssrc, const int* sdst,
                      f16* Xnext, float* out32, hipStream_t stream){
    constexpr int TPN = MPO / VEC;
    k_gemm_mfma<K, KP, MPH, HH><<<cdiv(NN, 64), 256, 0, stream>>>(
        Xh, Wpk, H2, Was, Wad, als, ald);
    if constexpr (EDGEATT){
        k_mz2<HH><<<cdiv((long)NN * HH, BS), BS, 0, stream>>>(als, ald, rowptr, ssrc, marr, zinv);
        k_att_edge<HH, ATTS, false><<<cdiv(ET, 256), 256, 0, stream>>>(
            als, ald, marr, zinv, ssrc, sdst, att);
    } else {
        k_mz_att<HH, ATTS><<<cdiv((long)NN * HH, BS), BS, 0, stream>>>(
            als, ald, rowptr, ssrc, att);
    }
    k_agg_h<HH, CC, ATTS, MPH, MPO, VEC, O16><<<cdiv((long)NN * TPN, 256), 256, 0, stream>>>(
        H2, att, rowptr, ssrc, bp, Xnext, out32, M);
}

extern "C" void kernel_launch(void* const* d_in, const int* in_sizes, int n_in,
                              void* d_out, int out_size, void* d_ws, size_t ws_size,
                              hipStream_t stream){
    const float* x0 = (const float*)d_in[0];
    const int*   ei = (const int*)d_in[1];
    PrepAll pa;
    for (int i = 0; i < 5; i++){
        pa.W[i]  = (const float*)d_in[3 + 4 * i];
        pa.b[i]  = (const float*)d_in[4 + 4 * i];
        pa.as[i] = (const float*)d_in[5 + 4 * i];
        pa.ad[i] = (const float*)d_in[6 + 4 * i];
    }

    char* p = (char*)d_ws;
    auto alloc = [&](size_t bytes) -> char* {
        char* r = p;
        p += (bytes + 255) & ~(size_t)255;
        return r;
    };
    f16*   Xh     = (f16*)alloc((size_t)NN * 256 * 2);
    f16*   H2     = (f16*)alloc((size_t)NN * 320 * 2);   // also holds Xagg (L0)
    f16*   att    = (f16*)alloc((size_t)ET * 16 * 2);
    float* als    = (float*)alloc((size_t)NN * 10 * 4);
    float* ald    = (float*)alloc((size_t)NN * 10 * 4);
    float* marr   = (float*)alloc((size_t)NN * 10 * 4);
    float* zinv   = (float*)alloc((size_t)NN * 10 * 4);
    const int wpkSz[5] = {7680, 32768, 8192, 2048, 512};
    const int mpSz[5]  = {240, 128, 64, 32, 16};
    const int khSz[5]  = {320, 1200, 240, 48, 24};
    for (int i = 0; i < 5; i++){
        pa.Wpk[i] = (f16*)alloc((size_t)wpkSz[i] * 2);
        pa.bp[i]  = (float*)alloc((size_t)mpSz[i] * 4);
        pa.Was[i] = (float*)alloc((size_t)khSz[i] * 4);
        pa.Wad[i] = (float*)alloc((size_t)khSz[i] * 4);
    }
    pa.Wpk0 = (f16*)alloc((size_t)10240 * 2);
    int*      bucketCount  = (int*)alloc((size_t)BKTS * 4);
    int*      bucketBase   = (int*)alloc((size_t)(BKTS + 1) * 4);
    int*      bucketCursor = (int*)alloc((size_t)BKTS * 4);
    unsigned* bpack        = (unsigned*)alloc((size_t)ET * 4);
    int*      rowptr       = (int*)alloc((size_t)(NN + 1) * 4);
    int*      ssrc         = (int*)alloc((size_t)ET * 4);
    int*      sdst         = (int*)alloc((size_t)ET * 4);
    pa.bucketCount = bucketCount;

    // ---- prep (+ zero bucketCount) + CSR build via 2-level counting sort ----
    k_prep_all<<<242, 256, 0, stream>>>(pa);
    k_bhist<<<cdiv(ET, FB_EPB), 256, 0, stream>>>(ei, bucketCount);
    k_bscan<<<1, 512, 0, stream>>>(bucketCount, bucketBase, bucketCursor, rowptr);
    k_bfill<<<cdiv(ET, FB_EPB), 256, 0, stream>>>(ei, bucketCursor, bpack);
    k_bsort<<<BKTS, 256, 0, stream>>>(bpack, bucketBase, rowptr, ssrc, sdst);

    // ---- Layer 0 via (A.X)@W identity ----
    k_cvt_alpha0<<<cdiv(NN, BS), BS, 0, stream>>>(x0, Xh, pa.Was[0], pa.Wad[0], als, ald);
    k_mz2<10><<<cdiv((long)NN * 10, BS), BS, 0, stream>>>(als, ald, rowptr, ssrc, marr, zinv);
    k_att_edge<10, 16, true><<<cdiv(ET, 256), 256, 0, stream>>>(
        als, ald, marr, zinv, ssrc, sdst, att);
    k_aggX0<<<cdiv((long)NN * 8, 256), 256, 0, stream>>>(Xh, att, rowptr, ssrc, H2 /*Xagg*/);
    dim3 g0(cdiv(NN, 128), 10);
    k_gemmX0<<<g0, 256, 0, stream>>>(H2 /*Xagg*/, pa.Wpk0, pa.bp[0], Xh /*X1, stride 256*/);

    // ---- Layers 1..4 (direct H-gather) ----
    //         K    M   KP  MPH  MPO  HH  CC ATTS VEC  O16   EDGEATT
    run_layer<240, 120, 256, 128, 128,  5, 24, 8, 8, true,  true >(Xh, H2, att, pa.Wpk[1],
        pa.bp[1], pa.Was[1], pa.Wad[1], als, ald, marr, zinv, rowptr, ssrc, sdst, Xh, nullptr, stream);
    run_layer<120,  48, 128,  64,  64,  2, 24, 2, 8, true,  false>(Xh, H2, att, pa.Wpk[2],
        pa.bp[2], pa.Was[2], pa.Wad[2], als, ald, marr, zinv, rowptr, ssrc, sdst, Xh, nullptr, stream);
    run_layer< 48,  24,  64,  32,  32,  1, 24, 1, 8, true,  false>(Xh, H2, att, pa.Wpk[3],
        pa.bp[3], pa.Was[3], pa.Wad[3], als, ald, marr, zinv, rowptr, ssrc, sdst, Xh, nullptr, stream);
    run_layer< 24,  12,  32,  16,  16,  1, 12, 1, 4, false, false>(Xh, H2, att, pa.Wpk[4],
        pa.bp[4], pa.Was[4], pa.Wad[4], als, ald, marr, zinv, rowptr, ssrc, sdst, nullptr, (float*)d_out, stream);
}

// Round 13
// 527.728 us; speedup vs baseline: 1.0953x; 1.0953x over previous
//
#include <hip/hip_runtime.h>
#include <math.h>

#define NN 100000
#define EE 800000
#define ET (EE + NN)
#define BS 256
#define BKTS 391        // cdiv(NN, 256) coarse buckets (dst >> 8)
#define FB_EPB 4096     // edges per block in hist/fill passes
#define LDSCAP 4096     // max edges per bucket (mean 2303, sigma ~45)

typedef _Float16 f16;
typedef __attribute__((ext_vector_type(4))) _Float16 half4;
typedef __attribute__((ext_vector_type(8))) _Float16 half8;
typedef __attribute__((ext_vector_type(4))) float f32x4;
template<int V> struct HV;
template<> struct HV<4>{ typedef half4 type; };
template<> struct HV<8>{ typedef half8 type; };

static inline int cdiv(long a, int b){ return (int)((a + b - 1) / b); }

// ---------------- CSR build: 2-level counting sort (no per-dst atomics) ----------------
__global__ __launch_bounds__(256) void k_bhist(const int* __restrict__ ei,
                                               int* __restrict__ bucketCount){
    __shared__ int hist[BKTS];
    for (int t = threadIdx.x; t < BKTS; t += 256) hist[t] = 0;
    __syncthreads();
    const int e0 = blockIdx.x * FB_EPB + threadIdx.x;
    #pragma unroll
    for (int i = 0; i < 16; i++){
        int e = e0 + i * 256;
        if (e < ET){
            int d = (e < EE) ? ei[EE + e] : (e - EE);
            atomicAdd(&hist[d >> 8], 1);
        }
    }
    __syncthreads();
    for (int t = threadIdx.x; t < BKTS; t += 256){
        int c = hist[t];
        if (c) atomicAdd(&bucketCount[t], c);
    }
}

__global__ void k_bscan(const int* __restrict__ bucketCount, int* __restrict__ bucketBase,
                        int* __restrict__ bucketCursor, int* __restrict__ rowptr){
    __shared__ int sh[512];
    int t = threadIdx.x;
    int c = (t < BKTS) ? bucketCount[t] : 0;
    sh[t] = c;
    __syncthreads();
    for (int o = 1; o < 512; o <<= 1){
        int v = (t >= o) ? sh[t - o] : 0;
        __syncthreads();
        sh[t] += v;
        __syncthreads();
    }
    if (t < BKTS){
        int excl = sh[t] - c;
        bucketBase[t] = excl;
        bucketCursor[t] = excl;
    }
    if (t == 0){
        bucketBase[BKTS] = ET;
        rowptr[NN] = ET;
    }
}

__global__ __launch_bounds__(256) void k_bfill(const int* __restrict__ ei,
        int* __restrict__ bucketCursor, unsigned* __restrict__ bpack){
    __shared__ int hist[BKTS];
    __shared__ int base[BKTS];
    for (int t = threadIdx.x; t < BKTS; t += 256) hist[t] = 0;
    __syncthreads();
    const int e0 = blockIdx.x * FB_EPB + threadIdx.x;
    unsigned pk[16], rb[16];
    #pragma unroll
    for (int i = 0; i < 16; i++){
        int e = e0 + i * 256;
        rb[i] = 0xFFFFFFFFu;
        if (e < ET){
            int s, d;
            if (e < EE){ s = ei[e]; d = ei[EE + e]; } else { s = e - EE; d = s; }
            int b = d >> 8;
            int r = atomicAdd(&hist[b], 1);
            pk[i] = ((unsigned)(d & 255) << 17) | (unsigned)s;
            rb[i] = ((unsigned)r << 9) | (unsigned)b;
        }
    }
    __syncthreads();
    for (int t = threadIdx.x; t < BKTS; t += 256){
        int c = hist[t];
        base[t] = c ? atomicAdd(&bucketCursor[t], c) : 0;
    }
    __syncthreads();
    #pragma unroll
    for (int i = 0; i < 16; i++){
        if (rb[i] != 0xFFFFFFFFu){
            int b = rb[i] & 511;
            int r = rb[i] >> 9;
            bpack[base[b] + r] = pk[i];
        }
    }
}

// Pass 4: block per bucket: LDS counting-sort by dstlow; coalesced rowptr+ssrc+sdst.
__global__ __launch_bounds__(256) void k_bsort(const unsigned* __restrict__ bpack,
        const int* __restrict__ bucketBase, int* __restrict__ rowptr,
        int* __restrict__ ssrc, int* __restrict__ sdst){
    __shared__ int cnt[256];
    __shared__ int off[256];
    __shared__ unsigned stage[LDSCAP];
    int b = blockIdx.x;
    int n0 = bucketBase[b], n1 = bucketBase[b + 1];
    int nE = n1 - n0;
    int t = threadIdx.x;
    cnt[t] = 0;
    __syncthreads();
    for (int i = t; i < nE; i += 256){
        unsigned v = bpack[n0 + i];
        atomicAdd(&cnt[v >> 17], 1);
    }
    __syncthreads();
    int cv = cnt[t];
    off[t] = cv;
    __syncthreads();
    for (int o = 1; o < 256; o <<= 1){
        int v = (t >= o) ? off[t - o] : 0;
        __syncthreads();
        off[t] += v;
        __syncthreads();
    }
    int excl = off[t] - cv;
    __syncthreads();
    off[t] = excl;
    cnt[t] = 0;
    __syncthreads();
    for (int i = t; i < nE; i += 256){
        unsigned v = bpack[n0 + i];
        int dl = v >> 17;
        int r = atomicAdd(&cnt[dl], 1);
        stage[off[dl] + r] = v;
    }
    int d = b * 256 + t;
    if (d < NN) rowptr[d] = n0 + excl;
    __syncthreads();
    for (int i = t; i < nE; i += 256){
        unsigned v = stage[i];
        ssrc[n0 + i] = (int)(v & 0x1FFFFu);
        sdst[n0 + i] = b * 256 + (int)(v >> 17);
    }
}

// ---------------- prep (all layers in one kernel) ----------------
template<int K, int M, int KP, int MP, int HH, int CC>
__device__ __forceinline__ void prep_one(int idx, const float* __restrict__ W,
        const float* __restrict__ b, const float* __restrict__ as_,
        const float* __restrict__ ad_, f16* __restrict__ Wpk,
        float* __restrict__ bp, float* __restrict__ Was, float* __restrict__ Wad){
    constexpr int NT = MP / 16;
    if (idx < KP * MP){
        int j    = idx & 7;
        int lane = (idx >> 3) & 63;
        int rest = idx >> 9;
        int nt   = rest % NT;
        int ks   = rest / NT;
        int k = ks * 32 + ((lane >> 4) & 3) * 8 + j;
        int n = nt * 16 + (lane & 15);
        Wpk[idx] = (k < K && n < M) ? (f16)W[k * M + n] : (f16)0.f;
    }
    if (idx < MP) bp[idx] = (idx < M) ? b[idx] : 0.f;
    if (idx < K * HH){
        int k = idx / HH, hd = idx - k * HH;
        float s = 0.f, d = 0.f;
        #pragma unroll
        for (int c = 0; c < CC; c++){
            float w = W[k * M + hd * CC + c];
            s = fmaf(w, as_[hd * CC + c], s);
            d = fmaf(w, ad_[hd * CC + c], d);
        }
        Was[idx] = s;
        Wad[idx] = d;
    }
}

__device__ __forceinline__ void prep_w0(int idx, const float* __restrict__ W0,
                                        f16* __restrict__ Wpk0){
    int j    = idx & 7;
    int lane = (idx >> 3) & 63;
    int nt   = (idx >> 9) & 1;
    int hd   = idx >> 10;
    int k    = ((lane >> 4) & 3) * 8 + j;
    int cih  = nt * 16 + (lane & 15);
    Wpk0[idx] = (cih < 24) ? (f16)W0[k * 240 + hd * 24 + cih] : (f16)0.f;
}

struct PrepAll {
    const float *W[5], *b[5], *as[5], *ad[5];
    f16*   Wpk[5];
    f16*   Wpk0;
    float* bp[5];
    float* Was[5];
    float* Wad[5];
    int*   bucketCount;
};

__global__ void k_prep_all(PrepAll a){
    int idx = blockIdx.x * 256 + threadIdx.x;
    if (idx < 7680)
        prep_one< 32, 240,  32, 240, 10, 24>(idx,         a.W[0], a.b[0], a.as[0], a.ad[0], a.Wpk[0], a.bp[0], a.Was[0], a.Wad[0]);
    else if (idx < 40448)
        prep_one<240, 120, 256, 128,  5, 24>(idx - 7680,  a.W[1], a.b[1], a.as[1], a.ad[1], a.Wpk[1], a.bp[1], a.Was[1], a.Wad[1]);
    else if (idx < 48640)
        prep_one<120,  48, 128,  64,  2, 24>(idx - 40448, a.W[2], a.b[2], a.as[2], a.ad[2], a.Wpk[2], a.bp[2], a.Was[2], a.Wad[2]);
    else if (idx < 50688)
        prep_one< 48,  24,  64,  32,  1, 24>(idx - 48640, a.W[3], a.b[3], a.as[3], a.ad[3], a.Wpk[3], a.bp[3], a.Was[3], a.Wad[3]);
    else if (idx < 51200)
        prep_one< 24,  12,  32,  16,  1, 12>(idx - 50688, a.W[4], a.b[4], a.as[4], a.ad[4], a.Wpk[4], a.bp[4], a.Was[4], a.Wad[4]);
    else if (idx < 61440)
        prep_w0(idx - 51200, a.W[0], a.Wpk0);
    else if (idx < 61440 + BKTS)
        a.bucketCount[idx - 61440] = 0;
}

// ---------------- L0: fused X0 fp32->fp16 convert + alpha logits ----------------
__global__ void k_cvt_alpha0(const float* __restrict__ X, f16* __restrict__ Xh,
                             const float* __restrict__ Was, const float* __restrict__ Wad,
                             float* __restrict__ als, float* __restrict__ ald){
    int n = blockIdx.x * BS + threadIdx.x;
    if (n >= NN) return;
    float xr[32];
    #pragma unroll
    for (int i = 0; i < 8; i++){
        float4 v = *(const float4*)(X + (long)n * 32 + i * 4);
        xr[i * 4 + 0] = v.x; xr[i * 4 + 1] = v.y;
        xr[i * 4 + 2] = v.z; xr[i * 4 + 3] = v.w;
    }
    #pragma unroll
    for (int i = 0; i < 4; i++){
        half8 h;
        #pragma unroll
        for (int c = 0; c < 8; c++) h[c] = (f16)xr[i * 8 + c];
        *(half8*)(Xh + (long)n * 32 + i * 8) = h;
    }
    float s[10] = {}, d[10] = {};
    for (int k = 0; k < 32; k++){
        float x = xr[k];
        #pragma unroll
        for (int hd = 0; hd < 10; hd++){
            s[hd] = fmaf(x, Was[k * 10 + hd], s[hd]);
            d[hd] = fmaf(x, Wad[k * 10 + hd], d[hd]);
        }
    }
    #pragma unroll
    for (int hd = 0; hd < 10; hd++){
        als[n * 10 + hd] = s[hd];
        ald[n * 10 + hd] = d[hd];
    }
}

// ---------------- alpha logits from H2 (layers 1..4): M MACs/node, linear reads ----------------
template<int MPH, int HH, int CC>
__global__ void k_alpha_h(const f16* __restrict__ H2, const float* __restrict__ as_,
                          const float* __restrict__ ad_, float* __restrict__ als,
                          float* __restrict__ ald){
    int n = blockIdx.x * BS + threadIdx.x;
    if (n >= NN) return;
    const f16* h = H2 + (long)n * MPH;
    #pragma unroll
    for (int hd = 0; hd < HH; hd++){
        float s = 0.f, d = 0.f;
        #pragma unroll
        for (int c0 = 0; c0 < CC; c0 += 4){
            half4 hv = *(const half4*)(h + hd * CC + c0);
            #pragma unroll
            for (int j = 0; j < 4; j++){
                float hvf = (float)hv[j];
                s = fmaf(hvf, as_[hd * CC + c0 + j], s);
                d = fmaf(hvf, ad_[hd * CC + c0 + j], d);
            }
        }
        als[n * HH + hd] = s;
        ald[n * HH + hd] = d;
    }
}

// ---------------- softmax state m, 1/z per (dst, head): 2 passes ----------------
template<int HH>
__global__ void k_mz2(const float* __restrict__ als, const float* __restrict__ ald,
                      const int* __restrict__ rowptr, const int* __restrict__ ssrc,
                      float* __restrict__ marr, float* __restrict__ zinvarr){
    int idx = blockIdx.x * BS + threadIdx.x;
    if (idx >= NN * HH) return;
    int n = idx / HH, hd = idx - n * HH;
    float adv = ald[idx];
    int beg = rowptr[n], end = rowptr[n + 1];
    float ma = -1e30f;
    for (int p = beg; p < end; p++)
        ma = fmaxf(ma, als[ssrc[p] * HH + hd]);
    float m = ma + adv;
    m = (m >= 0.f) ? m : 0.2f * m;
    float z = 0.f;
    for (int p = beg; p < end; p++){
        float e = als[ssrc[p] * HH + hd] + adv;
        e = (e >= 0.f) ? e : 0.2f * e;
        z += __expf(e - m);
    }
    marr[idx] = m;
    zinvarr[idx] = 1.f / z;
}

// ---------------- edge-parallel normalized attention (L0/L1): coalesced writes ----------------
template<int HH, int ATTS, bool GROUPED>
__global__ __launch_bounds__(256) void k_att_edge(const float* __restrict__ als,
        const float* __restrict__ ald, const float* __restrict__ marr,
        const float* __restrict__ zinv, const int* __restrict__ ssrc,
        const int* __restrict__ sdst, f16* __restrict__ att){
    int p = blockIdx.x * 256 + threadIdx.x;
    if (p >= ET) return;
    int s = ssrc[p], d = sdst[p];
    float w[HH];
    #pragma unroll
    for (int hd = 0; hd < HH; hd++){
        float e = als[s * HH + hd] + ald[d * HH + hd];
        e = (e >= 0.f) ? e : 0.2f * e;
        w[hd] = __expf(e - marr[d * HH + hd]) * zinv[d * HH + hd];
    }
    if constexpr (GROUPED){                 // HH==10, ATTS==16: heads 0-4 | 5-9
        half8 lo = {}, hi = {};
        #pragma unroll
        for (int h = 0; h < 5; h++){ lo[h] = (f16)w[h]; hi[h] = (f16)w[h + 5]; }
        *(half8*)(att + (long)p * 16)     = lo;
        *(half8*)(att + (long)p * 16 + 8) = hi;
    } else {                                // HH==5, ATTS==8
        half8 v = {};
        #pragma unroll
        for (int h = 0; h < HH; h++) v[h] = (f16)w[h];
        *(half8*)(att + (long)p * ATTS) = v;
    }
}

// ---------------- fused 3-pass mz+att (kept for HH<=2) ----------------
template<int HH, int ATTS>
__global__ void k_mz_att(const float* __restrict__ als, const float* __restrict__ ald,
                         const int* __restrict__ rowptr, const int* __restrict__ ssrc,
                         f16* __restrict__ att){
    int idx = blockIdx.x * BS + threadIdx.x;
    if (idx >= NN * HH) return;
    int n = idx / HH, hd = idx - n * HH;
    float adv = ald[idx];
    int beg = rowptr[n], end = rowptr[n + 1];
    float ma = -1e30f;
    for (int p = beg; p < end; p++)
        ma = fmaxf(ma, als[ssrc[p] * HH + hd]);
    float m = ma + adv;
    m = (m >= 0.f) ? m : 0.2f * m;
    float z = 0.f;
    for (int p = beg; p < end; p++){
        float e = als[ssrc[p] * HH + hd] + adv;
        e = (e >= 0.f) ? e : 0.2f * e;
        z += __expf(e - m);
    }
    float zinv = 1.f / z;
    for (int p = beg; p < end; p++){
        float e = als[ssrc[p] * HH + hd] + adv;
        e = (e >= 0.f) ? e : 0.2f * e;
        att[(long)p * ATTS + hd] = (f16)(__expf(e - m) * zinv);
    }
}

// ---------------- L0: aggregate X: Xagg[n,hd,k] = sum_s att * X[s,k] ----------------
__global__ __launch_bounds__(256) void k_aggX0(const f16* __restrict__ Xh,
        const f16* __restrict__ att, const int* __restrict__ rowptr,
        const int* __restrict__ ssrc, f16* __restrict__ Xagg){
    int idx = blockIdx.x * 256 + threadIdx.x;
    if (idx >= NN * 8) return;
    int n = idx >> 3;
    int hg = (idx >> 2) & 1;
    int ch = idx & 3;
    float acc[5][8] = {};
    int beg = rowptr[n], end = rowptr[n + 1];
    int p = beg;
    for (; p + 2 <= end; p += 2){
        int s0 = ssrc[p], s1 = ssrc[p + 1];
        half8 x0 = *(const half8*)(Xh + (long)s0 * 32 + ch * 8);
        half8 x1 = *(const half8*)(Xh + (long)s1 * 32 + ch * 8);
        half8 a0 = *(const half8*)(att + (long)p * 16 + hg * 8);
        half8 a1 = *(const half8*)(att + (long)(p + 1) * 16 + hg * 8);
        #pragma unroll
        for (int h = 0; h < 5; h++){
            float w0 = (float)a0[h], w1 = (float)a1[h];
            #pragma unroll
            for (int c = 0; c < 8; c++){
                acc[h][c] = fmaf(w0, (float)x0[c], acc[h][c]);
                acc[h][c] = fmaf(w1, (float)x1[c], acc[h][c]);
            }
        }
    }
    if (p < end){
        int s = ssrc[p];
        half8 xv = *(const half8*)(Xh + (long)s * 32 + ch * 8);
        half8 av = *(const half8*)(att + (long)p * 16 + hg * 8);
        #pragma unroll
        for (int h = 0; h < 5; h++){
            float w = (float)av[h];
            #pragma unroll
            for (int c = 0; c < 8; c++)
                acc[h][c] = fmaf(w, (float)xv[c], acc[h][c]);
        }
    }
    #pragma unroll
    for (int h = 0; h < 5; h++){
        half8 o;
        #pragma unroll
        for (int c = 0; c < 8; c++) o[c] = (f16)acc[h][c];
        *(half8*)(Xagg + (long)n * 320 + (hg * 5 + h) * 32 + ch * 8) = o;
    }
}

// ---------------- L0: block-diagonal MFMA GEMM: X1 = relu(Xagg @bd W0 + b) ----------------
__global__ __launch_bounds__(256) void k_gemmX0(const f16* __restrict__ Xagg,
        const f16* __restrict__ Wpk0, const float* __restrict__ bp0,
        f16* __restrict__ X1){
    const int wave = threadIdx.x >> 6;
    const int lane = threadIdx.x & 63;
    const int quad = lane >> 4;
    const int l16  = lane & 15;
    const int hd   = blockIdx.y;
    const long row0 = (long)blockIdx.x * 128 + wave * 32;
    const long r0 = row0 + l16;
    const long r1 = r0 + 16;
    const half8 hz = {};
    half8 a0 = (r0 < NN) ? *(const half8*)(Xagg + r0 * 320 + hd * 32 + quad * 8) : hz;
    half8 a1 = (r1 < NN) ? *(const half8*)(Xagg + r1 * 320 + hd * 32 + quad * 8) : hz;
    f32x4 acc[2][2];
    #pragma unroll
    for (int mt = 0; mt < 2; mt++)
        #pragma unroll
        for (int nt = 0; nt < 2; nt++)
            acc[mt][nt] = (f32x4){0.f, 0.f, 0.f, 0.f};
    #pragma unroll
    for (int nt = 0; nt < 2; nt++){
        half8 bfr = *(const half8*)(Wpk0 + ((hd * 2 + nt) * 64 + lane) * 8);
        acc[0][nt] = __builtin_amdgcn_mfma_f32_16x16x32_f16(a0, bfr, acc[0][nt], 0, 0, 0);
        acc[1][nt] = __builtin_amdgcn_mfma_f32_16x16x32_f16(a1, bfr, acc[1][nt], 0, 0, 0);
    }
    #pragma unroll
    for (int mt = 0; mt < 2; mt++){
        #pragma unroll
        for (int reg = 0; reg < 4; reg++){
            long r = row0 + mt * 16 + quad * 4 + reg;
            if (r < NN){
                #pragma unroll
                for (int nt = 0; nt < 2; nt++){
                    int cih = nt * 16 + l16;
                    if (cih < 24){
                        int j = hd * 24 + cih;
                        float v = acc[mt][nt][reg] + bp0[j];
                        X1[r * 256 + j] = (f16)((v > 0.f) ? v : 0.f);
                    }
                }
            }
        }
    }
}

// ---------------- MFMA GEMM v4 (layers 1..4): 128 rows/block, 2 m-tiles/wave,
// register double-buffer on BOTH A and B, no alpha tail ----------------
template<int KP, int MPH>
__global__ __launch_bounds__(256) void k_gemm_mfma(const f16* __restrict__ Xh,
        const f16* __restrict__ Wpk, f16* __restrict__ H2){
    constexpr int NT = MPH / 16;
    constexpr int KS = KP / 32;
    const int wave = threadIdx.x >> 6;
    const int lane = threadIdx.x & 63;
    const int quad = lane >> 4;
    const int l16  = lane & 15;
    const long row0 = (long)blockIdx.x * 128 + wave * 32;

    f32x4 acc[2][NT];
    #pragma unroll
    for (int mt = 0; mt < 2; mt++)
        #pragma unroll
        for (int nt = 0; nt < NT; nt++)
            acc[mt][nt] = (f32x4){0.f, 0.f, 0.f, 0.f};

    const long r0 = row0 + l16;
    const long r1 = row0 + 16 + l16;
    const half8 hz = {};
    // preload ks=0 (A pair + all NT B-fragments)
    half8 a0 = (r0 < NN) ? *(const half8*)(Xh + r0 * KP + quad * 8) : hz;
    half8 a1 = (r1 < NN) ? *(const half8*)(Xh + r1 * KP + quad * 8) : hz;
    half8 bc[NT];
    #pragma unroll
    for (int nt = 0; nt < NT; nt++)
        bc[nt] = *(const half8*)(Wpk + ((long)nt * 64 + lane) * 8);

    for (int ks = 0; ks < KS; ks++){
        half8 n0 = hz, n1 = hz, bn[NT];
        if (ks + 1 < KS){
            const int kk = (ks + 1) * 32 + quad * 8;
            n0 = (r0 < NN) ? *(const half8*)(Xh + r0 * KP + kk) : hz;
            n1 = (r1 < NN) ? *(const half8*)(Xh + r1 * KP + kk) : hz;
            const f16* bp_ = Wpk + ((long)(ks + 1) * NT * 64 + lane) * 8;
            #pragma unroll
            for (int nt = 0; nt < NT; nt++)
                bn[nt] = *(const half8*)(bp_ + (long)nt * 512);
        } else {
            #pragma unroll
            for (int nt = 0; nt < NT; nt++) bn[nt] = hz;
        }
        #pragma unroll
        for (int nt = 0; nt < NT; nt++){
            acc[0][nt] = __builtin_amdgcn_mfma_f32_16x16x32_f16(a0, bc[nt], acc[0][nt], 0, 0, 0);
            acc[1][nt] = __builtin_amdgcn_mfma_f32_16x16x32_f16(a1, bc[nt], acc[1][nt], 0, 0, 0);
        }
        a0 = n0; a1 = n1;
        #pragma unroll
        for (int nt = 0; nt < NT; nt++) bc[nt] = bn[nt];
    }
    #pragma unroll
    for (int mt = 0; mt < 2; mt++){
        #pragma unroll
        for (int reg = 0; reg < 4; reg++){
            long r = row0 + mt * 16 + quad * 4 + reg;
            if (r < NN){
                #pragma unroll
                for (int nt = 0; nt < NT; nt++)
                    H2[r * MPH + nt * 16 + l16] = (f16)acc[mt][nt][reg];
            }
        }
    }
}

// ---------------- fused aggregate via precomputed att (layers 1..4) ----------------
template<int HH, int CC, int ATTS, int MPH, int MPO, int VEC, bool O16>
__global__ __launch_bounds__(256) void k_agg_h(const f16* __restrict__ H2,
        const f16* __restrict__ att,
        const int* __restrict__ rowptr, const int* __restrict__ ssrc,
        const float* __restrict__ bp, f16* __restrict__ out16,
        float* __restrict__ out32, int MREAL){
    constexpr int TPN = MPO / VEC;
    typedef typename HV<VEC>::type hvec;
    int idx = blockIdx.x * 256 + threadIdx.x;
    if (idx >= NN * TPN) return;
    int n = idx / TPN;
    int q = idx - n * TPN;
    int j0 = q * VEC;
    if constexpr (O16 && (MPO > MPH)){
        if (j0 >= MPH){
            hvec zv = {};
            *(hvec*)(out16 + (long)n * MPO + j0) = zv;
            return;
        }
    }
    int hd = j0 / CC; if (hd > HH - 1) hd = HH - 1;

    int beg = rowptr[n], end = rowptr[n + 1];
    float acc[VEC] = {};
    int p = beg;
    for (; p + 2 <= end; p += 2){
        int s0 = ssrc[p], s1 = ssrc[p + 1];
        float w0 = (float)att[(long)p * ATTS + hd];
        float w1 = (float)att[(long)(p + 1) * ATTS + hd];
        hvec h0 = *(const hvec*)(H2 + (long)s0 * MPH + j0);
        hvec h1 = *(const hvec*)(H2 + (long)s1 * MPH + j0);
        #pragma unroll
        for (int c = 0; c < VEC; c++){
            acc[c] = fmaf(w0, (float)h0[c], acc[c]);
            acc[c] = fmaf(w1, (float)h1[c], acc[c]);
        }
    }
    if (p < end){
        int s = ssrc[p];
        float w = (float)att[(long)p * ATTS + hd];
        hvec hv = *(const hvec*)(H2 + (long)s * MPH + j0);
        #pragma unroll
        for (int c = 0; c < VEC; c++)
            acc[c] = fmaf(w, (float)hv[c], acc[c]);
    }
    if constexpr (O16){
        hvec o;
        #pragma unroll
        for (int c = 0; c < VEC; c++){
            float v = acc[c] + bp[j0 + c];
            o[c] = (f16)((v > 0.f) ? v : 0.f);
        }
        *(hvec*)(out16 + (long)n * MPO + j0) = o;
    } else {
        if (j0 < MREAL){
            #pragma unroll
            for (int c = 0; c < VEC; c++){
                float v = acc[c] + bp[j0 + c];
                out32[(long)n * MREAL + j0 + c] = (v > 0.f) ? v : 0.f;
            }
        }
    }
}

// ---------------- layer driver (layers 1..4) ----------------
template<int K, int M, int KP, int MPH, int MPO, int HH, int CC, int ATTS, int VEC,
         bool O16, bool EDGEATT>
static void run_layer(const f16* Xh, f16* H2, f16* att,
                      const f16* Wpk, const float* bp,
                      const float* asv, const float* adv,
                      float* als, float* ald, float* marr, float* zinv,
                      const int* rowptr, const int* ssrc, const int* sdst,
                      f16* Xnext, float* out32, hipStream_t stream){
    constexpr int TPN = MPO / VEC;
    k_gemm_mfma<KP, MPH><<<cdiv(NN, 128), 256, 0, stream>>>(Xh, Wpk, H2);
    k_alpha_h<MPH, HH, CC><<<cdiv(NN, BS), BS, 0, stream>>>(H2, asv, adv, als, ald);
    if constexpr (EDGEATT){
        k_mz2<HH><<<cdiv((long)NN * HH, BS), BS, 0, stream>>>(als, ald, rowptr, ssrc, marr, zinv);
        k_att_edge<HH, ATTS, false><<<cdiv(ET, 256), 256, 0, stream>>>(
            als, ald, marr, zinv, ssrc, sdst, att);
    } else {
        k_mz_att<HH, ATTS><<<cdiv((long)NN * HH, BS), BS, 0, stream>>>(
            als, ald, rowptr, ssrc, att);
    }
    k_agg_h<HH, CC, ATTS, MPH, MPO, VEC, O16><<<cdiv((long)NN * TPN, 256), 256, 0, stream>>>(
        H2, att, rowptr, ssrc, bp, Xnext, out32, M);
}

extern "C" void kernel_launch(void* const* d_in, const int* in_sizes, int n_in,
                              void* d_out, int out_size, void* d_ws, size_t ws_size,
                              hipStream_t stream){
    const float* x0 = (const float*)d_in[0];
    const int*   ei = (const int*)d_in[1];
    PrepAll pa;
    for (int i = 0; i < 5; i++){
        pa.W[i]  = (const float*)d_in[3 + 4 * i];
        pa.b[i]  = (const float*)d_in[4 + 4 * i];
        pa.as[i] = (const float*)d_in[5 + 4 * i];
        pa.ad[i] = (const float*)d_in[6 + 4 * i];
    }

    char* p = (char*)d_ws;
    auto alloc = [&](size_t bytes) -> char* {
        char* r = p;
        p += (bytes + 255) & ~(size_t)255;
        return r;
    };
    f16*   Xh     = (f16*)alloc((size_t)NN * 256 * 2);
    f16*   H2     = (f16*)alloc((size_t)NN * 320 * 2);   // also holds Xagg (L0)
    f16*   att    = (f16*)alloc((size_t)ET * 16 * 2);
    float* als    = (float*)alloc((size_t)NN * 10 * 4);
    float* ald    = (float*)alloc((size_t)NN * 10 * 4);
    float* marr   = (float*)alloc((size_t)NN * 10 * 4);
    float* zinv   = (float*)alloc((size_t)NN * 10 * 4);
    const int wpkSz[5] = {7680, 32768, 8192, 2048, 512};
    const int mpSz[5]  = {240, 128, 64, 32, 16};
    const int khSz[5]  = {320, 1200, 240, 48, 24};
    for (int i = 0; i < 5; i++){
        pa.Wpk[i] = (f16*)alloc((size_t)wpkSz[i] * 2);
        pa.bp[i]  = (float*)alloc((size_t)mpSz[i] * 4);
        pa.Was[i] = (float*)alloc((size_t)khSz[i] * 4);
        pa.Wad[i] = (float*)alloc((size_t)khSz[i] * 4);
    }
    pa.Wpk0 = (f16*)alloc((size_t)10240 * 2);
    int*      bucketCount  = (int*)alloc((size_t)BKTS * 4);
    int*      bucketBase   = (int*)alloc((size_t)(BKTS + 1) * 4);
    int*      bucketCursor = (int*)alloc((size_t)BKTS * 4);
    unsigned* bpack        = (unsigned*)alloc((size_t)ET * 4);
    int*      rowptr       = (int*)alloc((size_t)(NN + 1) * 4);
    int*      ssrc         = (int*)alloc((size_t)ET * 4);
    int*      sdst         = (int*)alloc((size_t)ET * 4);
    pa.bucketCount = bucketCount;

    // ---- prep (+ zero bucketCount) + CSR build via 2-level counting sort ----
    k_prep_all<<<242, 256, 0, stream>>>(pa);
    k_bhist<<<cdiv(ET, FB_EPB), 256, 0, stream>>>(ei, bucketCount);
    k_bscan<<<1, 512, 0, stream>>>(bucketCount, bucketBase, bucketCursor, rowptr);
    k_bfill<<<cdiv(ET, FB_EPB), 256, 0, stream>>>(ei, bucketCursor, bpack);
    k_bsort<<<BKTS, 256, 0, stream>>>(bpack, bucketBase, rowptr, ssrc, sdst);

    // ---- Layer 0 via (A.X)@W identity ----
    k_cvt_alpha0<<<cdiv(NN, BS), BS, 0, stream>>>(x0, Xh, pa.Was[0], pa.Wad[0], als, ald);
    k_mz2<10><<<cdiv((long)NN * 10, BS), BS, 0, stream>>>(als, ald, rowptr, ssrc, marr, zinv);
    k_att_edge<10, 16, true><<<cdiv(ET, 256), 256, 0, stream>>>(
        als, ald, marr, zinv, ssrc, sdst, att);
    k_aggX0<<<cdiv((long)NN * 8, 256), 256, 0, stream>>>(Xh, att, rowptr, ssrc, H2 /*Xagg*/);
    dim3 g0(cdiv(NN, 128), 10);
    k_gemmX0<<<g0, 256, 0, stream>>>(H2 /*Xagg*/, pa.Wpk0, pa.bp[0], Xh /*X1, stride 256*/);

    // ---- Layers 1..4 (direct H-gather) ----
    //         K    M   KP  MPH  MPO  HH  CC ATTS VEC  O16   EDGEATT
    run_layer<240, 120, 256, 128, 128,  5, 24, 8, 8, true,  true >(Xh, H2, att, pa.Wpk[1],
        pa.bp[1], pa.as[1], pa.ad[1], als, ald, marr, zinv, rowptr, ssrc, sdst, Xh, nullptr, stream);
    run_layer<120,  48, 128,  64,  64,  2, 24, 2, 8, true,  false>(Xh, H2, att, pa.Wpk[2],
        pa.bp[2], pa.as[2], pa.ad[2], als, ald, marr, zinv, rowptr, ssrc, sdst, Xh, nullptr, stream);
    run_layer< 48,  24,  64,  32,  32,  1, 24, 1, 8, true,  false>(Xh, H2, att, pa.Wpk[3],
        pa.bp[3], pa.as[3], pa.ad[3], als, ald, marr, zinv, rowptr, ssrc, sdst, Xh, nullptr, stream);
    run_layer< 24,  12,  32,  16,  16,  1, 12, 1, 4, false, false>(Xh, H2, att, pa.Wpk[4],
        pa.bp[4], pa.as[4], pa.ad[4], als, ald, marr, zinv, rowptr, ssrc, sdst, nullptr, (float*)d_out, stream);
}